// Round 7
// baseline (1177.700 us; speedup 1.0000x reference)
//
#include <hip/hip_runtime.h>
#include <math.h>

#define NN 50000
#define NE 640000
#define NR 8
#define SCAN_N (NN * NR)  // 400000 segments
#define SCAN_CH 2048      // elements per scan block
#define SCAN_NB ((SCAN_N + SCAN_CH - 1) / SCAN_CH)  // 196

typedef __attribute__((ext_vector_type(8))) _Float16 half8;
typedef __attribute__((ext_vector_type(8))) short short8;
typedef __attribute__((ext_vector_type(4))) float f32x4;

__device__ __forceinline__ unsigned short f2h(float f) {
    _Float16 h = (_Float16)f;                       // v_cvt_f16_f32, RNE
    return __builtin_bit_cast(unsigned short, h);
}
__device__ __forceinline__ float h2f(unsigned short u) {
    return (float)__builtin_bit_cast(_Float16, u);
}

// ---------- preprocessing ----------
__global__ __launch_bounds__(256) void count_kernel(const int* __restrict__ dst,
                                                    const int* __restrict__ typ,
                                                    int* __restrict__ cnt, int E) {
    int e = blockIdx.x * 256 + threadIdx.x;
    if (e < E) atomicAdd(&cnt[dst[e] * NR + typ[e]], 1);
}

// ---- hierarchical scan
__global__ __launch_bounds__(256) void scan1_kernel(const int* __restrict__ cnt,
                                                    int* __restrict__ loc,
                                                    int* __restrict__ bsum) {
    __shared__ int s[256];
    const int t = threadIdx.x;
    const int base = blockIdx.x * SCAN_CH + t * 8;
    int v[8];
    int sum = 0;
#pragma unroll
    for (int j = 0; j < 8; ++j) {
        int idx = base + j;
        v[j] = (idx < SCAN_N) ? cnt[idx] : 0;
        sum += v[j];
    }
    s[t] = sum;
    __syncthreads();
    for (int off = 1; off < 256; off <<= 1) {
        int u = (t >= off) ? s[t - off] : 0;
        __syncthreads();
        s[t] += u;
        __syncthreads();
    }
    int run = (t == 0) ? 0 : s[t - 1];
#pragma unroll
    for (int j = 0; j < 8; ++j) {
        int idx = base + j;
        if (idx < SCAN_N) loc[idx] = run;
        run += v[j];
    }
    if (t == 255) bsum[blockIdx.x] = s[255];
}

__global__ __launch_bounds__(256) void scan2_kernel(const int* __restrict__ bsum,
                                                    int* __restrict__ boff, int nb) {
    __shared__ int s[256];
    const int t = threadIdx.x;
    s[t] = (t < nb) ? bsum[t] : 0;
    __syncthreads();
    for (int off = 1; off < 256; off <<= 1) {
        int u = (t >= off) ? s[t - off] : 0;
        __syncthreads();
        s[t] += u;
        __syncthreads();
    }
    if (t < nb) boff[t] = (t == 0) ? 0 : s[t - 1];
    if (t == nb - 1) boff[nb] = s[t];
}

__global__ __launch_bounds__(256) void scan3_kernel(int* __restrict__ rowptr,
                                                    int* __restrict__ start,
                                                    const int* __restrict__ boff, int nb) {
    const int b = blockIdx.x, t = threadIdx.x;
    const int add = boff[b];
#pragma unroll
    for (int j = 0; j < 8; ++j) {
        int idx = b * SCAN_CH + t * 8 + j;
        if (idx < SCAN_N) {
            int v = rowptr[idx] + add;
            rowptr[idx] = v;
            start[idx] = v;
        }
    }
    if (b == 0 && t == 0) rowptr[SCAN_N] = boff[nb];
}

// counting-sort by (dst,rel): srcrel[pos] = src | rel<<20
__global__ __launch_bounds__(256) void fill_kernel(const int* __restrict__ src,
                                                   const int* __restrict__ dst,
                                                   const int* __restrict__ typ,
                                                   int* __restrict__ start,
                                                   int* __restrict__ srcrel, int E) {
    int e = blockIdx.x * 256 + threadIdx.x;
    if (e >= E) return;
    int r = typ[e];
    int pos = atomicAdd(&start[dst[e] * NR + r], 1);
    srcrel[pos] = src[e] | (r << 20);
}

// ---------- x (fp32, [NN,128]) -> xh (fp16) ----------
__global__ __launch_bounds__(256) void cvt_kernel(const float* __restrict__ x,
                                                  unsigned short* __restrict__ xh, int n4) {
    int i = blockIdx.x * 256 + threadIdx.x;
    if (i >= n4) return;
    float4 v = ((const float4*)x)[i];
    uint2 u;
    u.x = (unsigned)f2h(v.x) | ((unsigned)f2h(v.y) << 16);
    u.y = (unsigned)f2h(v.z) | ((unsigned)f2h(v.w) << 16);
    ((uint2*)xh)[i] = u;
}

// ---------- weight pack: Bt[n][k] fp16, n in [0,9*O): n<8*O -> W[r=n/O][k][o=n%O], else root[k][n-8*O]
__global__ __launch_bounds__(256) void pack_b_kernel(const float* __restrict__ W,
                                                     const float* __restrict__ root,
                                                     unsigned short* __restrict__ Bt, int O) {
    int i = blockIdx.x * 256 + threadIdx.x;
    int NTOT = 9 * O;
    if (i >= NTOT * 128) return;
    int k = i & 127, n = i >> 7;
    float v = (n < 8 * O) ? W[(size_t)(n / O) * 128 * O + (size_t)k * O + (n % O)]
                          : root[(size_t)k * O + (n - 8 * O)];
    Bt[(size_t)n * 128 + k] = f2h(v);
}

// ---------- fused aggregate-first RGCN layer ----------
// h[dst] = sum_r (mean_{src in N_r(dst)} X[src]) @ W_r + X[dst] @ root + b  (+ sigmoid)
// Block: 16 dst, 16 waves (1024 thr), 64.5 KB LDS -> 2 blocks/CU (32 waves/CU).
// Phase 1: ONE dst per wave (round-0's proven agg mapping), flat 4-unrolled
// gather loop. Relation separation via fire-and-forget LDS float atomics
// (ds_add_f32, no return): per edge = gather + 2 cvt + 2 ds_add. NO per-edge
// register accumulator chain and NO relation dispatch in registers -- the
// r3-r6 plateau (155-163 us) came from the 8-way relation accumulation
// (switch OR select-FMA fan), which the compiler serialized to 1 gather in
// flight. fp32 tile de-interleaved (x half then y half) so ds_add addresses
// are stride-4 conflict-free.
// Phase 1.5: scale by 1/cnt (from rp bounds -- no inv buffer), convert to
// XOR-swizzled fp16 tile in lower 32 KB (reads->regs, barrier, writes).
// Phase 2: 16xO GEMM, K=9*128 (root streamed from global), MFMA 16x16x32 f16,
// 16 waves = col-tiles x K-groups, LDS partial reduce in pbuf (aliases upper
// 32 KB, free after convert).
#define DS_ACC(P, G)                                                          \
    do {                                                                      \
        unsigned rel_ = ((unsigned)(P)) >> 20;                                \
        float* b_ = rowb + rel_ * 128 + lane;                                 \
        atomicAdd(b_, h2f((unsigned short)((G) & 0xFFFFu)));                  \
        atomicAdd(b_ + 64, h2f((unsigned short)((G) >> 16)));                 \
    } while (0)

template <int O, bool FINAL>
__global__ __launch_bounds__(1024, 8) void fused_layer(
    const int* __restrict__ rp, const int* __restrict__ srcrel,
    const unsigned short* __restrict__ X, const unsigned short* __restrict__ Bt,
    const float* __restrict__ bias, void* __restrict__ Hout) {
    __shared__ __align__(16) char ldsbuf[16 * 1024 * 4];  // 64 KB
    __shared__ float ivtab[16][8];
    float* As32 = (float*)ldsbuf;                  // [16][1024] de-interleaved
    unsigned short* As16 = (unsigned short*)ldsbuf;  // lower 32 KB after cvt
    float* pbuf = (float*)(ldsbuf + 32768);        // upper 32 KB, phase-2 only
    const int t = threadIdx.x;
    const int w = t >> 6, lane = t & 63;
    const int bm = blockIdx.x * 16;                // 50000 % 16 == 0
    const unsigned* X2 = (const unsigned*)X;       // half2 view, row stride 64

    // ---- zero the fp32 accumulation tile ----
#pragma unroll
    for (int k = 0; k < 16; ++k) As32[t + k * 1024] = 0.f;
    __syncthreads();

    // ---- phase 1: wave w aggregates dst bm+w (round-0 loop shape) ----
    {
        const int d = bm + w;
        const int r8 = d * 8;
        if (lane < 8) {
            int c = rp[r8 + lane + 1] - rp[r8 + lane];
            ivtab[w][lane] = 1.f / (float)(c > 1 ? c : 1);
        }
        float* rowb = As32 + w * 1024;
        const int beg = rp[r8], end = rp[r8 + 8];
        int i = beg;
        for (; i + 3 < end; i += 4) {   // 4 gathers pipelined, no acc chain
            int p0 = srcrel[i], p1 = srcrel[i + 1];
            int p2 = srcrel[i + 2], p3 = srcrel[i + 3];
            unsigned g0 = X2[(size_t)(p0 & 0xFFFFF) * 64 + lane];
            unsigned g1 = X2[(size_t)(p1 & 0xFFFFF) * 64 + lane];
            unsigned g2 = X2[(size_t)(p2 & 0xFFFFF) * 64 + lane];
            unsigned g3 = X2[(size_t)(p3 & 0xFFFFF) * 64 + lane];
            DS_ACC(p0, g0);
            DS_ACC(p1, g1);
            DS_ACC(p2, g2);
            DS_ACC(p3, g3);
        }
        for (; i < end; ++i) {
            int p0 = srcrel[i];
            unsigned g0 = X2[(size_t)(p0 & 0xFFFFF) * 64 + lane];
            DS_ACC(p0, g0);
        }
    }
    __syncthreads();

    // ---- phase 1.5: scale + fp32 -> swizzled fp16 (in place, lower 32 KB) ----
    {
        const int m = w, l = lane;
        float xv[8], yv[8], ivr[8];
#pragma unroll
        for (int r = 0; r < 8; ++r) {
            xv[r] = As32[m * 1024 + r * 128 + l];
            yv[r] = As32[m * 1024 + r * 128 + 64 + l];
            ivr[r] = ivtab[m][r];
        }
        __syncthreads();   // all reads done before fp16 overwrites
        char* rowp = (char*)As16 + m * 2048;
        const int swz = (m & 7) << 4;
#pragma unroll
        for (int r = 0; r < 8; ++r) {
            unsigned u = (unsigned)f2h(xv[r] * ivr[r]) |
                         ((unsigned)f2h(yv[r] * ivr[r]) << 16);
            *(unsigned*)(rowp + ((r * 256 + l * 4) ^ swz)) = u;
        }
    }
    __syncthreads();

    // ---- phase 2: [16 x 9*128] @ Bt^T -> [16 x O], 16 waves ----
    const int q = lane >> 4, ml = lane & 15;
    int col, ksb, kg, ci;
    if (O == 128) {            // 8 col tiles x 2 K-groups of 18 ksteps
        ci = w & 7; col = ci * 16; kg = w >> 3; ksb = kg * 18;
    } else {                   // 4 col tiles x 4 K-groups of 9 ksteps
        ci = w & 3; col = ci * 16; kg = w >> 2; ksb = kg * 9;
    }
    constexpr int NKS = (O == 128) ? 18 : 9;

    f32x4 acc0 = (f32x4)0.f, acc1 = (f32x4)0.f;
    const unsigned short* Xroot = X + (size_t)(bm + ml) * 128;
    const char* arowp = (const char*)As16 + ml * 2048;
    const int aswz = (ml & 7) << 4;

#pragma unroll
    for (int u = 0; u < NKS; ++u) {
        int ks = ksb + u;
        int r = ks >> 2, kk = ks & 3;
        half8 af;
        if (r < 8) {
            af = __builtin_bit_cast(
                half8,
                *(const short8*)(arowp + ((r * 256 + kk * 64 + q * 16) ^ aswz)));
        } else {
            af = __builtin_bit_cast(half8,
                                    *(const short8*)(Xroot + kk * 32 + q * 8));
        }
        half8 bf = __builtin_bit_cast(
            half8,
            *(const short8*)(Bt + (size_t)(r * O + col + ml) * 128 + kk * 32 +
                             q * 8));
        if (u & 1)
            acc1 = __builtin_amdgcn_mfma_f32_16x16x32_f16(af, bf, acc1, 0, 0, 0);
        else
            acc0 = __builtin_amdgcn_mfma_f32_16x16x32_f16(af, bf, acc0, 0, 0, 0);
    }
    f32x4 accv = acc0 + acc1;

    // epilogue: C/D layout col=lane&15, row=q*4+j; K-group reduce via pbuf
    if (kg != 0) {
#pragma unroll
        for (int j = 0; j < 4; ++j)
            pbuf[((kg - 1) * ((O == 128) ? 8 : 4) + ci) * 256 +
                 (q * 4 + j) * 16 + ml] = accv[j];
    }
    __syncthreads();
    if (kg == 0) {
        float bv = bias[col + ml];
#pragma unroll
        for (int j = 0; j < 4; ++j) {
            int grow = bm + q * 4 + j;
            float v = accv[j] + bv;
            if (O == 128) {
                v += pbuf[ci * 256 + (q * 4 + j) * 16 + ml];
            } else {
                v += pbuf[(0 * 4 + ci) * 256 + (q * 4 + j) * 16 + ml];
                v += pbuf[(1 * 4 + ci) * 256 + (q * 4 + j) * 16 + ml];
                v += pbuf[(2 * 4 + ci) * 256 + (q * 4 + j) * 16 + ml];
            }
            if (FINAL)
                ((float*)Hout)[(size_t)grow * O + col + ml] =
                    1.f / (1.f + __expf(-v));
            else
                ((unsigned short*)Hout)[(size_t)grow * O + col + ml] = f2h(v);
        }
    }
}

extern "C" void kernel_launch(void* const* d_in, const int* in_sizes, int n_in,
                              void* d_out, int out_size, void* d_ws, size_t ws_size,
                              hipStream_t stream) {
    const float* x     = (const float*)d_in[0];
    const int*   esrc  = (const int*)d_in[1];
    const int*   edst  = (const int*)d_in[2];
    const int*   etyp  = (const int*)d_in[3];
    const float* W1    = (const float*)d_in[4];
    const float* root1 = (const float*)d_in[5];
    const float* b1    = (const float*)d_in[6];
    const float* W2    = (const float*)d_in[7];
    const float* root2 = (const float*)d_in[8];
    const float* b2    = (const float*)d_in[9];
    float* out = (float*)d_out;

    char* ws = (char*)d_ws;
    unsigned short* Bt1    = (unsigned short*)ws; ws += (size_t)1152 * 128 * 2; // 288 KB
    unsigned short* Bt2    = (unsigned short*)ws; ws += (size_t)576 * 128 * 2;  // 144 KB
    int*            cnt    = (int*)ws;            ws += (size_t)SCAN_N * 4;     // 1.6 MB
    int*            rp     = (int*)ws;            ws += (size_t)(SCAN_N + 64) * 4;
    int*            start  = (int*)ws;            ws += (size_t)SCAN_N * 4;     // 1.6 MB
    int*            bsum   = (int*)ws;            ws += (size_t)256 * 4;
    int*            boff   = (int*)ws;            ws += (size_t)257 * 4;
    int*            srcrel = (int*)ws;            ws += (size_t)NE * 4;         // 2.56 MB
    unsigned short* xh     = (unsigned short*)ws; ws += (size_t)NN * 128 * 2;   // 12.8 MB
    unsigned short* h1b    = (unsigned short*)ws;                               // 12.8 MB

    // CSR by (dst, rel) — hierarchical scan, fully parallel
    hipMemsetAsync(cnt, 0, (size_t)SCAN_N * 4, stream);
    count_kernel<<<(NE + 255) / 256, 256, 0, stream>>>(edst, etyp, cnt, NE);
    scan1_kernel<<<SCAN_NB, 256, 0, stream>>>(cnt, rp, bsum);
    scan2_kernel<<<1, 256, 0, stream>>>(bsum, boff, SCAN_NB);
    scan3_kernel<<<SCAN_NB, 256, 0, stream>>>(rp, start, boff, SCAN_NB);
    fill_kernel<<<(NE + 255) / 256, 256, 0, stream>>>(esrc, edst, etyp, start, srcrel, NE);

    // fp16 conversions / packs
    cvt_kernel<<<(NN * 32 + 255) / 256, 256, 0, stream>>>(x, xh, NN * 32);
    pack_b_kernel<<<(1152 * 128 + 255) / 256, 256, 0, stream>>>(W1, root1, Bt1, 128);
    pack_b_kernel<<<(576 * 128 + 255) / 256, 256, 0, stream>>>(W2, root2, Bt2, 64);

    const int fgrid = NN / 16;  // 3125 blocks of 16 dst, 1024 threads

    // layer 1: aggregate-first fused (mean_r(x) @ W_r + x @ root1 + b1) -> h1b fp16
    fused_layer<128, false><<<fgrid, 1024, 0, stream>>>(rp, srcrel, xh, Bt1, b1, h1b);
    // layer 2: same on h1b, + sigmoid -> out fp32
    fused_layer<64, true><<<fgrid, 1024, 0, stream>>>(rp, srcrel, h1b, Bt2, b2, out);
}

// Round 8
// 434.332 us; speedup vs baseline: 2.7115x; 2.7115x over previous
//
#include <hip/hip_runtime.h>
#include <math.h>

#define NN 50000
#define NE 640000
#define NR 8
#define SCAN_N (NN * NR)  // 400000 segments
#define SCAN_CH 2048      // elements per scan block
#define SCAN_NB ((SCAN_N + SCAN_CH - 1) / SCAN_CH)  // 196

typedef __attribute__((ext_vector_type(8))) _Float16 half8;
typedef __attribute__((ext_vector_type(8))) short short8;
typedef __attribute__((ext_vector_type(4))) float f32x4;

__device__ __forceinline__ unsigned short f2h(float f) {
    _Float16 h = (_Float16)f;                       // v_cvt_f16_f32, RNE
    return __builtin_bit_cast(unsigned short, h);
}
__device__ __forceinline__ float h2f(unsigned short u) {
    return (float)__builtin_bit_cast(_Float16, u);
}

// ---------- preprocessing ----------
__global__ __launch_bounds__(256) void count_kernel(const int* __restrict__ dst,
                                                    const int* __restrict__ typ,
                                                    int* __restrict__ cnt, int E) {
    int e = blockIdx.x * 256 + threadIdx.x;
    if (e < E) atomicAdd(&cnt[dst[e] * NR + typ[e]], 1);
}

// ---- hierarchical scan
__global__ __launch_bounds__(256) void scan1_kernel(const int* __restrict__ cnt,
                                                    int* __restrict__ loc,
                                                    int* __restrict__ bsum) {
    __shared__ int s[256];
    const int t = threadIdx.x;
    const int base = blockIdx.x * SCAN_CH + t * 8;
    int v[8];
    int sum = 0;
#pragma unroll
    for (int j = 0; j < 8; ++j) {
        int idx = base + j;
        v[j] = (idx < SCAN_N) ? cnt[idx] : 0;
        sum += v[j];
    }
    s[t] = sum;
    __syncthreads();
    for (int off = 1; off < 256; off <<= 1) {
        int u = (t >= off) ? s[t - off] : 0;
        __syncthreads();
        s[t] += u;
        __syncthreads();
    }
    int run = (t == 0) ? 0 : s[t - 1];
#pragma unroll
    for (int j = 0; j < 8; ++j) {
        int idx = base + j;
        if (idx < SCAN_N) loc[idx] = run;
        run += v[j];
    }
    if (t == 255) bsum[blockIdx.x] = s[255];
}

__global__ __launch_bounds__(256) void scan2_kernel(const int* __restrict__ bsum,
                                                    int* __restrict__ boff, int nb) {
    __shared__ int s[256];
    const int t = threadIdx.x;
    s[t] = (t < nb) ? bsum[t] : 0;
    __syncthreads();
    for (int off = 1; off < 256; off <<= 1) {
        int u = (t >= off) ? s[t - off] : 0;
        __syncthreads();
        s[t] += u;
        __syncthreads();
    }
    if (t < nb) boff[t] = (t == 0) ? 0 : s[t - 1];
    if (t == nb - 1) boff[nb] = s[t];
}

__global__ __launch_bounds__(256) void scan3_kernel(int* __restrict__ rowptr,
                                                    int* __restrict__ start,
                                                    const int* __restrict__ boff, int nb) {
    const int b = blockIdx.x, t = threadIdx.x;
    const int add = boff[b];
#pragma unroll
    for (int j = 0; j < 8; ++j) {
        int idx = b * SCAN_CH + t * 8 + j;
        if (idx < SCAN_N) {
            int v = rowptr[idx] + add;
            rowptr[idx] = v;
            start[idx] = v;
        }
    }
    if (b == 0 && t == 0) rowptr[SCAN_N] = boff[nb];
}

// counting-sort by (dst,rel): srcrel[pos] = src | rel<<20
__global__ __launch_bounds__(256) void fill_kernel(const int* __restrict__ src,
                                                   const int* __restrict__ dst,
                                                   const int* __restrict__ typ,
                                                   int* __restrict__ start,
                                                   int* __restrict__ srcrel, int E) {
    int e = blockIdx.x * 256 + threadIdx.x;
    if (e >= E) return;
    int r = typ[e];
    int pos = atomicAdd(&start[dst[e] * NR + r], 1);
    srcrel[pos] = src[e] | (r << 20);
}

// ---------- x (fp32, [NN,128]) -> xh (fp16) ----------
__global__ __launch_bounds__(256) void cvt_kernel(const float* __restrict__ x,
                                                  unsigned short* __restrict__ xh, int n4) {
    int i = blockIdx.x * 256 + threadIdx.x;
    if (i >= n4) return;
    float4 v = ((const float4*)x)[i];
    uint2 u;
    u.x = (unsigned)f2h(v.x) | ((unsigned)f2h(v.y) << 16);
    u.y = (unsigned)f2h(v.z) | ((unsigned)f2h(v.w) << 16);
    ((uint2*)xh)[i] = u;
}

// ---------- weight pack: Bt[n][k] fp16, n in [0,9*O): n<8*O -> W[r=n/O][k][o=n%O], else root[k][n-8*O]
__global__ __launch_bounds__(256) void pack_b_kernel(const float* __restrict__ W,
                                                     const float* __restrict__ root,
                                                     unsigned short* __restrict__ Bt, int O) {
    int i = blockIdx.x * 256 + threadIdx.x;
    int NTOT = 9 * O;
    if (i >= NTOT * 128) return;
    int k = i & 127, n = i >> 7;
    float v = (n < 8 * O) ? W[(size_t)(n / O) * 128 * O + (size_t)k * O + (n % O)]
                          : root[(size_t)k * O + (n - 8 * O)];
    Bt[(size_t)n * 128 + k] = f2h(v);
}

// ---------- fused aggregate-first RGCN layer ----------
// h[dst] = sum_r (mean_{src in N_r(dst)} X[src]) @ W_r + X[dst] @ root + b (+ sigmoid)
// Block: 16 dst, 16 waves (1024 thr), ~44 KB LDS -> 2 blocks/CU (32 waves/CU).
// Phase 1: ONE dst per wave. KEY INSIGHT (r3-r7 post-mortems): the CSR is
// already sorted by (dst,rel) -- rp[d*8+r] delimits each relation's segment,
// so relation separation is FREE. Per segment we run a clone of round-0's
// proven gather loop (the only loop ever measured fast: <52us for this volume):
// single (ax,ay) accumulator, per edge = gather + 2 adds. NO switch, NO
// select-FMA fan, NO atomics -- all three serialized the pipeline (155-538us).
// Edge records and rowptrs are pre-batched into lane vectors (1 load each) and
// pulled via readlane (SGPR dynamic index), removing the per-edge load->gather
// chain. Flush per segment: scale by 1/cnt, f2h, one swizzled LDS row store.
// Phase 2: 16xO GEMM, K=9*128 (root streamed from global), MFMA 16x16x32 f16,
// 16 waves = col-tiles x K-groups, pbuf partial reduce.
template <int O, bool FINAL>
__global__ __launch_bounds__(1024, 8) void fused_layer(
    const int* __restrict__ rp, const int* __restrict__ srcrel,
    const unsigned short* __restrict__ X, const unsigned short* __restrict__ Bt,
    const float* __restrict__ bias, void* __restrict__ Hout) {
    __shared__ __align__(16) unsigned short As[16 * 1024];   // 32 KB fp16
    __shared__ float pbuf[FINAL ? 12 * 256 : 8 * 256];       // 12 / 8 KB
    const int t = threadIdx.x;
    const int w = t >> 6, lane = t & 63;
    const int bm = blockIdx.x * 16;                // 50000 % 16 == 0
    const unsigned* X2 = (const unsigned*)X;       // half2 view, row stride 64

    // ---- phase 1: wave w aggregates dst bm+w, segment by segment ----
    {
        const int d = bm + w, r8 = d * 8;
        // batch rowptrs: lanes 0..8 hold rp[r8..r8+8]  (one load)
        int rpv = rp[r8 + (lane < 8 ? lane : 8)];
        const int beg = __builtin_amdgcn_readlane(rpv, 0);
        int bb = beg;                      // edge-record batch base
        int pv = srcrel[bb + lane];        // one load covers <=64 edge records
        char* rowp = (char*)As + w * 2048;
        const int swz = (w & 7) << 4;
        int sb = beg;
        for (int r = 0; r < 8; ++r) {
            const int se = __builtin_amdgcn_readlane(rpv, r + 1);
            float ax = 0.f, ay = 0.f;
            int i = sb;
            while (i < se) {
                if (i - bb >= 64) { bb = i; pv = srcrel[bb + lane]; }
                int wend = (bb + 64 < se) ? bb + 64 : se;
                for (; i + 3 < wend; i += 4) {   // round-0 shape: 4-deep, 1 acc pair
                    int j0 = i - bb;
                    int p0 = __builtin_amdgcn_readlane(pv, j0);
                    int p1 = __builtin_amdgcn_readlane(pv, j0 + 1);
                    int p2 = __builtin_amdgcn_readlane(pv, j0 + 2);
                    int p3 = __builtin_amdgcn_readlane(pv, j0 + 3);
                    unsigned g0 = X2[(size_t)(p0 & 0xFFFFF) * 64 + lane];
                    unsigned g1 = X2[(size_t)(p1 & 0xFFFFF) * 64 + lane];
                    unsigned g2 = X2[(size_t)(p2 & 0xFFFFF) * 64 + lane];
                    unsigned g3 = X2[(size_t)(p3 & 0xFFFFF) * 64 + lane];
                    ax += h2f((unsigned short)(g0 & 0xFFFFu));
                    ay += h2f((unsigned short)(g0 >> 16));
                    ax += h2f((unsigned short)(g1 & 0xFFFFu));
                    ay += h2f((unsigned short)(g1 >> 16));
                    ax += h2f((unsigned short)(g2 & 0xFFFFu));
                    ay += h2f((unsigned short)(g2 >> 16));
                    ax += h2f((unsigned short)(g3 & 0xFFFFu));
                    ay += h2f((unsigned short)(g3 >> 16));
                }
                for (; i < wend; ++i) {
                    int p0 = __builtin_amdgcn_readlane(pv, i - bb);
                    unsigned g0 = X2[(size_t)(p0 & 0xFFFFF) * 64 + lane];
                    ax += h2f((unsigned short)(g0 & 0xFFFFu));
                    ay += h2f((unsigned short)(g0 >> 16));
                }
            }
            // mean scale + fp16 pack + swizzled row store (conflict-free)
            int c = se - sb;
            float iv = 1.0f / (float)(c > 1 ? c : 1);
            unsigned u = (unsigned)f2h(ax * iv) | ((unsigned)f2h(ay * iv) << 16);
            *(unsigned*)(rowp + ((r * 256 + lane * 4) ^ swz)) = u;
            sb = se;
        }
    }
    __syncthreads();

    // ---- phase 2: [16 x 9*128] @ Bt^T -> [16 x O], 16 waves ----
    const int q = lane >> 4, ml = lane & 15;
    int col, ksb, kg, ci;
    if (O == 128) {            // 8 col tiles x 2 K-groups of 18 ksteps
        ci = w & 7; col = ci * 16; kg = w >> 3; ksb = kg * 18;
    } else {                   // 4 col tiles x 4 K-groups of 9 ksteps
        ci = w & 3; col = ci * 16; kg = w >> 2; ksb = kg * 9;
    }
    constexpr int NKS = (O == 128) ? 18 : 9;

    f32x4 acc0 = (f32x4)0.f, acc1 = (f32x4)0.f;
    const unsigned short* Xroot = X + (size_t)(bm + ml) * 128;
    const char* arowp = (const char*)As + ml * 2048;
    const int aswz = (ml & 7) << 4;

#pragma unroll
    for (int u = 0; u < NKS; ++u) {
        int ks = ksb + u;
        int r = ks >> 2, kk = ks & 3;
        half8 af;
        if (r < 8) {
            af = __builtin_bit_cast(
                half8,
                *(const short8*)(arowp + ((r * 256 + kk * 64 + q * 16) ^ aswz)));
        } else {
            af = __builtin_bit_cast(half8,
                                    *(const short8*)(Xroot + kk * 32 + q * 8));
        }
        half8 bf = __builtin_bit_cast(
            half8,
            *(const short8*)(Bt + (size_t)(r * O + col + ml) * 128 + kk * 32 +
                             q * 8));
        if (u & 1)
            acc1 = __builtin_amdgcn_mfma_f32_16x16x32_f16(af, bf, acc1, 0, 0, 0);
        else
            acc0 = __builtin_amdgcn_mfma_f32_16x16x32_f16(af, bf, acc0, 0, 0, 0);
    }
    f32x4 accv = acc0 + acc1;

    // epilogue: C/D layout col=lane&15, row=q*4+j; K-group reduce via pbuf
    if (kg != 0) {
#pragma unroll
        for (int j = 0; j < 4; ++j)
            pbuf[((kg - 1) * ((O == 128) ? 8 : 4) + ci) * 256 +
                 (q * 4 + j) * 16 + ml] = accv[j];
    }
    __syncthreads();
    if (kg == 0) {
        float bv = bias[col + ml];
#pragma unroll
        for (int j = 0; j < 4; ++j) {
            int grow = bm + q * 4 + j;
            float v = accv[j] + bv;
            if (O == 128) {
                v += pbuf[ci * 256 + (q * 4 + j) * 16 + ml];
            } else {
                v += pbuf[(0 * 4 + ci) * 256 + (q * 4 + j) * 16 + ml];
                v += pbuf[(1 * 4 + ci) * 256 + (q * 4 + j) * 16 + ml];
                v += pbuf[(2 * 4 + ci) * 256 + (q * 4 + j) * 16 + ml];
            }
            if (FINAL)
                ((float*)Hout)[(size_t)grow * O + col + ml] =
                    1.f / (1.f + __expf(-v));
            else
                ((unsigned short*)Hout)[(size_t)grow * O + col + ml] = f2h(v);
        }
    }
}

extern "C" void kernel_launch(void* const* d_in, const int* in_sizes, int n_in,
                              void* d_out, int out_size, void* d_ws, size_t ws_size,
                              hipStream_t stream) {
    const float* x     = (const float*)d_in[0];
    const int*   esrc  = (const int*)d_in[1];
    const int*   edst  = (const int*)d_in[2];
    const int*   etyp  = (const int*)d_in[3];
    const float* W1    = (const float*)d_in[4];
    const float* root1 = (const float*)d_in[5];
    const float* b1    = (const float*)d_in[6];
    const float* W2    = (const float*)d_in[7];
    const float* root2 = (const float*)d_in[8];
    const float* b2    = (const float*)d_in[9];
    float* out = (float*)d_out;

    char* ws = (char*)d_ws;
    unsigned short* Bt1    = (unsigned short*)ws; ws += (size_t)1152 * 128 * 2; // 288 KB
    unsigned short* Bt2    = (unsigned short*)ws; ws += (size_t)576 * 128 * 2;  // 144 KB
    int*            cnt    = (int*)ws;            ws += (size_t)SCAN_N * 4;     // 1.6 MB
    int*            rp     = (int*)ws;            ws += (size_t)(SCAN_N + 64) * 4;
    int*            start  = (int*)ws;            ws += (size_t)SCAN_N * 4;     // 1.6 MB
    int*            bsum   = (int*)ws;            ws += (size_t)256 * 4;
    int*            boff   = (int*)ws;            ws += (size_t)257 * 4;
    int*            srcrel = (int*)ws;            ws += (size_t)(NE + 64) * 4;  // +64 pad for batch over-read
    unsigned short* xh     = (unsigned short*)ws; ws += (size_t)NN * 128 * 2;   // 12.8 MB
    unsigned short* h1b    = (unsigned short*)ws;                               // 12.8 MB

    // CSR by (dst, rel) — hierarchical scan, fully parallel
    hipMemsetAsync(cnt, 0, (size_t)SCAN_N * 4, stream);
    count_kernel<<<(NE + 255) / 256, 256, 0, stream>>>(edst, etyp, cnt, NE);
    scan1_kernel<<<SCAN_NB, 256, 0, stream>>>(cnt, rp, bsum);
    scan2_kernel<<<1, 256, 0, stream>>>(bsum, boff, SCAN_NB);
    scan3_kernel<<<SCAN_NB, 256, 0, stream>>>(rp, start, boff, SCAN_NB);
    fill_kernel<<<(NE + 255) / 256, 256, 0, stream>>>(esrc, edst, etyp, start, srcrel, NE);

    // fp16 conversions / packs
    cvt_kernel<<<(NN * 32 + 255) / 256, 256, 0, stream>>>(x, xh, NN * 32);
    pack_b_kernel<<<(1152 * 128 + 255) / 256, 256, 0, stream>>>(W1, root1, Bt1, 128);
    pack_b_kernel<<<(576 * 128 + 255) / 256, 256, 0, stream>>>(W2, root2, Bt2, 64);

    const int fgrid = NN / 16;  // 3125 blocks of 16 dst, 1024 threads

    // layer 1: aggregate-first fused (mean_r(x) @ W_r + x @ root1 + b1) -> h1b fp16
    fused_layer<128, false><<<fgrid, 1024, 0, stream>>>(rp, srcrel, xh, Bt1, b1, h1b);
    // layer 2: same on h1b, + sigmoid -> out fp32
    fused_layer<64, true><<<fgrid, 1024, 0, stream>>>(rp, srcrel, h1b, Bt2, b2, out);
}